// Round 5
// baseline (598.536 us; speedup 1.0000x reference)
//
#include <hip/hip_runtime.h>
#include <float.h>
#include <math.h>

// Problem constants (fixed by the reference)
#define NB 1024      // number of graphs B
#define HD 64        // feature dim H
#define NSTEPS 5
#define RT 9         // register-cached tiles per wave (9*16*8 waves = 1152 nodes max cached)

__device__ __forceinline__ float sigmoidf_(float x) {
    return 1.0f / (1.0f + __expf(-x));
}

// ---------------- segment boundaries from sorted batch ----------------
__global__ void seg_bounds_kernel(const int* __restrict__ batch,
                                  int* __restrict__ seg_start, int n) {
    int i = blockIdx.x * blockDim.x + threadIdx.x;
    if (i >= n) return;
    int b = batch[i];
    if (i == 0) {
        for (int j = 0; j <= b; ++j) seg_start[j] = 0;
    } else {
        int pb = batch[i - 1];
        for (int j = pb + 1; j <= b; ++j) seg_start[j] = i;
    }
    if (i == n - 1) {
        for (int j = b + 1; j <= NB; ++j) seg_start[j] = n;
    }
}

// Online-softmax update for accumulator set U with value XV (float4 of 4 features)
// of node NODE (segment-local index). mm/ss/rr are static-indexed register arrays.
#define ONLINE_UPD(U, XV, NODE)                                         \
    {                                                                   \
        float d = (XV).x * q4.x;                                        \
        d = fmaf((XV).y, q4.y, d);                                      \
        d = fmaf((XV).z, q4.z, d);                                      \
        d = fmaf((XV).w, q4.w, d);                                      \
        d += __shfl_xor(d, 1);                                          \
        d += __shfl_xor(d, 2);                                          \
        d += __shfl_xor(d, 4);                                          \
        d += __shfl_xor(d, 8);                                          \
        bool valid = (NODE) < len;                                      \
        float eeff = valid ? d : -FLT_MAX;                              \
        float nm = fmaxf(mm[U], eeff);                                  \
        float sc = __expf(mm[U] - nm);                                  \
        float w = valid ? __expf(eeff - nm) : 0.0f;                     \
        ss[U] = fmaf(ss[U], sc, w);                                     \
        rr[U].x = fmaf(rr[U].x, sc, w * (XV).x);                        \
        rr[U].y = fmaf(rr[U].y, sc, w * (XV).y);                        \
        rr[U].z = fmaf(rr[U].z, sc, w * (XV).z);                        \
        rr[U].w = fmaf(rr[U].w, sc, w * (XV).w);                        \
        mm[U] = nm;                                                     \
    }

// One block == one graph. x is loaded from HBM ONCE into a per-wave register
// cache (float4 xr[36] = 144 VGPRs); all 5 Set2Set steps read it from registers.
// h, c, r live in LDS.
// __launch_bounds__(512) (no min-occupancy arg): to guarantee launchability of
// a 512-thread block (8 waves/CU = 2/SIMD) the backend caps at 256 VGPRs --
// exactly the budget the cache needs. R2's (512,2) was interpreted as 2
// blocks/CU -> 128-VGPR cap -> the cache spilled to scratch (VGPR_Count=128,
// dur regressed to 347us, VALUBusy fell).
__global__ __launch_bounds__(512) void set2set_fused_kernel(
    const float* __restrict__ x,     // [N,64]
    const int* __restrict__ seg,     // [NB+1]
    const float* __restrict__ W_ih,  // [256,128]
    const float* __restrict__ W_hh,  // [256,64]
    const float* __restrict__ b_ih,  // [256]
    const float* __restrict__ b_hh,  // [256]
    const float* __restrict__ W1,    // [256,128]
    const float* __restrict__ b1,    // [256]
    const float* __restrict__ W2,    // [128,256]
    const float* __restrict__ b2,    // [128]
    float* __restrict__ out)         // [NB,128]
{
    __shared__ __align__(16) float hs[HD], cs[HD], rs[HD];
    __shared__ __align__(16) float gates[256], gpart[256];
    __shared__ __align__(16) float lr[8][HD];
    __shared__ float lm[8], ls[8];

    const int b = blockIdx.x;
    const int tid = threadIdx.x;
    const int lane = tid & 63;
    const int wv = tid >> 6;           // wave 0..7
    const int fc = lane & 15;          // feature chunk (4 floats)
    const int grp = lane >> 4;         // node subgroup 0..3

    const int s0 = seg[b], e0 = seg[b + 1];
    const int len = e0 - s0;
    const int ntiles = (len + 15) >> 4;     // 16-node tiles
    const int maxidx4 = e0 * 16 - 1;        // clamp (global float4 index), e0>0 always

    // ---- load this wave's tiles into the register cache, all issued up-front ----
    // Tile t is handled by wave (t & 7); cache slot j holds tile wv + 8*j.
    // Lane l of slot j,u holds features [fc*4,fc*4+4) of node-local (u*4+grp).
    float4 xr[4 * RT];
#pragma unroll
    for (int j = 0; j < RT; ++j) {
        int t = wv + 8 * j;
        if (t < ntiles) {
            int tb4 = (s0 + t * 16) * 16;
#pragma unroll
            for (int u = 0; u < 4; ++u) {
                int g4 = min(tb4 + u * 64 + lane, maxidx4);
                xr[4 * j + u] = *(const float4*)(x + (size_t)g4 * 4);
            }
        }
    }

    if (tid < HD) { hs[tid] = 0.0f; cs[tid] = 0.0f; rs[tid] = 0.0f; }
    __syncthreads();

    for (int step = 0; step < NSTEPS; ++step) {
        // ---- LSTM cell: gates = W_ih*[h|r] + W_hh*h + biases ----
        if (step == 0) {
            // q_star = h = 0 -> gates are pure bias
            if (tid < 256) gates[tid] = b_ih[tid] + b_hh[tid];
        } else {
            float acc = 0.0f;
            if (tid < 256) {
                acc = b_ih[tid] + b_hh[tid];
                const float4* w = (const float4*)(W_ih + tid * 128);
                const float4* hq = (const float4*)hs;
                const float4* rq = (const float4*)rs;
#pragma unroll
                for (int k = 0; k < 16; ++k) {
                    float4 ww = w[k]; float4 v = hq[k];
                    acc = fmaf(ww.x, v.x, acc); acc = fmaf(ww.y, v.y, acc);
                    acc = fmaf(ww.z, v.z, acc); acc = fmaf(ww.w, v.w, acc);
                }
#pragma unroll
                for (int k = 0; k < 16; ++k) {
                    float4 ww = w[16 + k]; float4 v = rq[k];
                    acc = fmaf(ww.x, v.x, acc); acc = fmaf(ww.y, v.y, acc);
                    acc = fmaf(ww.z, v.z, acc); acc = fmaf(ww.w, v.w, acc);
                }
            } else {
                int j = tid - 256;
                float a2 = 0.0f;
                const float4* w = (const float4*)(W_hh + j * 64);
                const float4* hq = (const float4*)hs;
#pragma unroll
                for (int k = 0; k < 16; ++k) {
                    float4 ww = w[k]; float4 v = hq[k];
                    a2 = fmaf(ww.x, v.x, a2); a2 = fmaf(ww.y, v.y, a2);
                    a2 = fmaf(ww.z, v.z, a2); a2 = fmaf(ww.w, v.w, a2);
                }
                gpart[j] = a2;
            }
            __syncthreads();
            if (tid < 256) gates[tid] = acc + gpart[tid];
        }
        __syncthreads();

        if (tid < HD) {
            float ig = sigmoidf_(gates[tid]);
            float fg = sigmoidf_(gates[tid + 64]);
            float gg = tanhf(gates[tid + 128]);
            float og = sigmoidf_(gates[tid + 192]);
            float cp = (step == 0) ? 0.0f : cs[tid];
            float cn = fmaf(fg, cp, ig * gg);
            cs[tid] = cn;
            hs[tid] = og * tanhf(cn);
        }
        __syncthreads();

        // ---- attention over this graph's nodes (q = h), from the register cache ----
        float4 q4 = *(const float4*)(hs + fc * 4);
        // 4 independent online-softmax accumulator sets (one per node subgroup slot u)
        float mm[4], ss[4];
        float4 rr[4];
#pragma unroll
        for (int u = 0; u < 4; ++u) {
            mm[u] = -FLT_MAX; ss[u] = 0.0f;
            rr[u] = make_float4(0.0f, 0.0f, 0.0f, 0.0f);
        }

#pragma unroll
        for (int j = 0; j < RT; ++j) {
            int t = wv + 8 * j;
            if (t < ntiles) {
                int nbase = t * 16;
                ONLINE_UPD(0, xr[4 * j + 0], nbase + 0 * 4 + grp);
                ONLINE_UPD(1, xr[4 * j + 1], nbase + 1 * 4 + grp);
                ONLINE_UPD(2, xr[4 * j + 2], nbase + 2 * 4 + grp);
                ONLINE_UPD(3, xr[4 * j + 3], nbase + 3 * 4 + grp);
            }
        }
        // overflow tiles beyond the register cache (rare): stream from global (L3-hot)
        for (int t = 8 * RT + wv; t < ntiles; t += 8) {
            int tb4 = (s0 + t * 16) * 16;
            int nbase = t * 16;
#pragma unroll
            for (int u = 0; u < 4; ++u) {
                int g4 = min(tb4 + u * 64 + lane, maxidx4);
                float4 xv = *(const float4*)(x + (size_t)g4 * 4);
                ONLINE_UPD(u, xv, nbase + u * 4 + grp);
            }
        }

        // merge the 4 accumulator sets within the lane
        float m = mm[0], sum = ss[0];
        float4 r4 = rr[0];
#pragma unroll
        for (int u = 1; u < 4; ++u) {
            float nm = fmaxf(m, mm[u]);
            float s1 = __expf(m - nm);
            float s2 = __expf(mm[u] - nm);
            sum = sum * s1 + ss[u] * s2;
            r4.x = r4.x * s1 + rr[u].x * s2;
            r4.y = r4.y * s1 + rr[u].y * s2;
            r4.z = r4.z * s1 + rr[u].z * s2;
            r4.w = r4.w * s1 + rr[u].w * s2;
            m = nm;
        }
        // merge the 4 node-subgroups within the wave (lanes with equal fc)
#pragma unroll
        for (int off = 16; off < 64; off <<= 1) {
            float om = __shfl_xor(m, off);
            float os = __shfl_xor(sum, off);
            float ox = __shfl_xor(r4.x, off);
            float oy = __shfl_xor(r4.y, off);
            float oz = __shfl_xor(r4.z, off);
            float ow = __shfl_xor(r4.w, off);
            float nm = fmaxf(m, om);
            float s1 = __expf(m - nm);
            float s2 = __expf(om - nm);
            sum = sum * s1 + os * s2;
            r4.x = r4.x * s1 + ox * s2;
            r4.y = r4.y * s1 + oy * s2;
            r4.z = r4.z * s1 + oz * s2;
            r4.w = r4.w * s1 + ow * s2;
            m = nm;
        }
        if (lane < 16) {
            if (lane == 0) { lm[wv] = m; ls[wv] = sum; }
            *(float4*)&lr[wv][lane * 4] = r4;
        }
        __syncthreads();

        // merge 8 wave partials -> normalized r (stays in LDS)
        if (tid < HD) {
            float M = lm[0];
#pragma unroll
            for (int w = 1; w < 8; ++w) M = fmaxf(M, lm[w]);
            float S = 0.0f, rf = 0.0f;
#pragma unroll
            for (int w = 0; w < 8; ++w) {
                float ww = __expf(lm[w] - M);
                S = fmaf(ls[w], ww, S);
                rf = fmaf(lr[w][tid], ww, rf);
            }
            rs[tid] = rf / fmaxf(S, 1e-16f);
        }
        __syncthreads();
    }

    // ---- MLP head: out = relu([h|r] @ W1^T + b1) @ W2^T + b2 ----
    if (tid < 256) {
        float acc = b1[tid];
        const float4* w = (const float4*)(W1 + tid * 128);
        const float4* hq = (const float4*)hs;
        const float4* rq = (const float4*)rs;
#pragma unroll
        for (int k = 0; k < 16; ++k) {
            float4 ww = w[k]; float4 v = hq[k];
            acc = fmaf(ww.x, v.x, acc); acc = fmaf(ww.y, v.y, acc);
            acc = fmaf(ww.z, v.z, acc); acc = fmaf(ww.w, v.w, acc);
        }
#pragma unroll
        for (int k = 0; k < 16; ++k) {
            float4 ww = w[16 + k]; float4 v = rq[k];
            acc = fmaf(ww.x, v.x, acc); acc = fmaf(ww.y, v.y, acc);
            acc = fmaf(ww.z, v.z, acc); acc = fmaf(ww.w, v.w, acc);
        }
        gates[tid] = fmaxf(acc, 0.0f);   // reuse as hidden activations
    }
    __syncthreads();
    if (tid < 128) {
        float acc = b2[tid];
        const float4* w = (const float4*)(W2 + tid * 256);
        const float4* hq = (const float4*)gates;
#pragma unroll 8
        for (int k = 0; k < 64; ++k) {
            float4 ww = w[k]; float4 v = hq[k];
            acc = fmaf(ww.x, v.x, acc); acc = fmaf(ww.y, v.y, acc);
            acc = fmaf(ww.z, v.z, acc); acc = fmaf(ww.w, v.w, acc);
        }
        out[b * 128 + tid] = acc;
    }
}

extern "C" void kernel_launch(void* const* d_in, const int* in_sizes, int n_in,
                              void* d_out, int out_size, void* d_ws, size_t ws_size,
                              hipStream_t stream) {
    const float* x     = (const float*)d_in[0];   // [N,64]
    const int*   batch = (const int*)d_in[1];     // [N] sorted
    const float* W_ih  = (const float*)d_in[2];   // [256,128]
    const float* W_hh  = (const float*)d_in[3];   // [256,64]
    const float* b_ih  = (const float*)d_in[4];
    const float* b_hh  = (const float*)d_in[5];
    const float* W1    = (const float*)d_in[6];   // [256,128]
    const float* b1    = (const float*)d_in[7];
    const float* W2    = (const float*)d_in[8];   // [128,256]
    const float* b2    = (const float*)d_in[9];
    float* out = (float*)d_out;
    const int N = in_sizes[1];

    int* seg = (int*)d_ws;   // NB+1 ints

    seg_bounds_kernel<<<(N + 255) / 256, 256, 0, stream>>>(batch, seg, N);
    set2set_fused_kernel<<<NB, 512, 0, stream>>>(x, seg, W_ih, W_hh, b_ih, b_hh,
                                                 W1, b1, W2, b2, out);
}

// Round 6
// 576.881 us; speedup vs baseline: 1.0375x; 1.0375x over previous
//
#include <hip/hip_runtime.h>
#include <float.h>
#include <math.h>

// Problem constants (fixed by the reference)
#define NB 1024      // number of graphs B
#define HD 64        // feature dim H
#define NSTEPS 5
#define LT 36        // LDS-cached tiles (16 nodes each): nodes 0..575, 144 KB
#define RT2 4        // register-cached tiles per wave: tiles LT..LT+31 (nodes 576..1087)

__device__ __forceinline__ float sigmoidf_(float x) {
    return 1.0f / (1.0f + __expf(-x));
}

// ---------------- segment boundaries from sorted batch ----------------
__global__ void seg_bounds_kernel(const int* __restrict__ batch,
                                  int* __restrict__ seg_start, int n) {
    int i = blockIdx.x * blockDim.x + threadIdx.x;
    if (i >= n) return;
    int b = batch[i];
    if (i == 0) {
        for (int j = 0; j <= b; ++j) seg_start[j] = 0;
    } else {
        int pb = batch[i - 1];
        for (int j = pb + 1; j <= b; ++j) seg_start[j] = i;
    }
    if (i == n - 1) {
        for (int j = b + 1; j <= NB; ++j) seg_start[j] = n;
    }
}

// async 16B/lane global->LDS: LDS base wave-uniform (HW adds lane*16),
// global source address is per-lane.
__device__ __forceinline__ void async_ld16(const float* g, float* l) {
    __builtin_amdgcn_global_load_lds(
        (const __attribute__((address_space(1))) void*)g,
        (__attribute__((address_space(3))) void*)l, 16, 0, 0);
}

// Online-softmax update for accumulator set U with value XV (float4 of 4 features)
// of node NODE (segment-local index). mm/ss/rr are static-indexed register arrays.
#define ONLINE_UPD(U, XV, NODE)                                         \
    {                                                                   \
        float d = (XV).x * q4.x;                                        \
        d = fmaf((XV).y, q4.y, d);                                      \
        d = fmaf((XV).z, q4.z, d);                                      \
        d = fmaf((XV).w, q4.w, d);                                      \
        d += __shfl_xor(d, 1);                                          \
        d += __shfl_xor(d, 2);                                          \
        d += __shfl_xor(d, 4);                                          \
        d += __shfl_xor(d, 8);                                          \
        bool valid = (NODE) < len;                                      \
        float eeff = valid ? d : -FLT_MAX;                              \
        float nm = fmaxf(mm[U], eeff);                                  \
        float sc = __expf(mm[U] - nm);                                  \
        float w = valid ? __expf(eeff - nm) : 0.0f;                     \
        ss[U] = fmaf(ss[U], sc, w);                                     \
        rr[U].x = fmaf(rr[U].x, sc, w * (XV).x);                        \
        rr[U].y = fmaf(rr[U].y, sc, w * (XV).y);                        \
        rr[U].z = fmaf(rr[U].z, sc, w * (XV).z);                        \
        rr[U].w = fmaf(rr[U].w, sc, w * (XV).w);                        \
        mm[U] = nm;                                                     \
    }

// One block == one graph. x is read from HBM ONCE into a hybrid on-chip cache:
//   - LDS:       tiles 0..LT-1   (576 nodes, 144 KB) via global_load_lds
//   - registers: tiles LT..LT+31 (512 nodes, 64 VGPR/lane)
// All 5 Set2Set steps then run from LDS + registers; h,c,r stay in LDS.
// The 149 KB LDS usage caps occupancy at 1 block/CU (2 waves/EU), which is
// what lifts the register allocator's budget to 256 VGPRs (R2/R5 showed the
// default heuristic targets 4 waves/EU = 128 VGPRs and spills the cache).
__global__ __attribute__((amdgpu_flat_work_group_size(512, 512)))
__attribute__((amdgpu_waves_per_eu(2, 2)))
void set2set_fused_kernel(
    const float* __restrict__ x,     // [N,64]
    const int* __restrict__ seg,     // [NB+1]
    const float* __restrict__ W_ih,  // [256,128]
    const float* __restrict__ W_hh,  // [256,64]
    const float* __restrict__ b_ih,  // [256]
    const float* __restrict__ b_hh,  // [256]
    const float* __restrict__ W1,    // [256,128]
    const float* __restrict__ b1,    // [256]
    const float* __restrict__ W2,    // [128,256]
    const float* __restrict__ b2,    // [128]
    float* __restrict__ out)         // [NB,128]
{
    __shared__ __align__(16) float xl[LT * 16 * HD];   // 144 KB node cache
    __shared__ __align__(16) float hs[HD], cs[HD], rs[HD];
    __shared__ __align__(16) float gates[256], gpart[256];
    __shared__ __align__(16) float lr[8][HD];
    __shared__ float lm[8], ls[8];

    const int b = blockIdx.x;
    const int tid = threadIdx.x;
    const int lane = tid & 63;
    const int wv = tid >> 6;           // wave 0..7
    const int fc = lane & 15;          // feature chunk (4 floats)
    const int grp = lane >> 4;         // node subgroup 0..3

    const int s0 = seg[b], e0 = seg[b + 1];
    const int len = e0 - s0;
    const int ntiles = (len + 15) >> 4;          // 16-node tiles
    const int maxidx4 = max(e0 * 16 - 1, 0);     // clamp (global float4 index)
    const int ltiles = min(LT, ntiles);          // tiles resident in LDS

    // ---- register cache: tiles LT + wv + 8*j ----
    // Lane l of slot (j,u) holds features [fc*4,fc*4+4) of node-local (u*4+grp).
    float4 xr[4 * RT2];
#pragma unroll
    for (int j = 0; j < RT2; ++j) {
        int t = LT + wv + 8 * j;
        if (t < ntiles) {
            int tb4 = (s0 + t * 16) * 16;
#pragma unroll
            for (int u = 0; u < 4; ++u) {
                int g4 = min(tb4 + u * 64 + lane, maxidx4);
                xr[4 * j + u] = *(const float4*)(x + (size_t)g4 * 4);
            }
        }
    }
    // ---- LDS cache: tiles wv, wv+8, ... < ltiles, via async global->LDS DMA ----
    // Tile t occupies xl[t*1024 .. t*1024+1024): node-major, 64 floats/node --
    // exactly the linear lane-order global_load_lds writes (dst + lane*16B).
    for (int t = wv; t < ltiles; t += 8) {
        int tb4 = (s0 + t * 16) * 16;
        float* dst = xl + t * 1024;
#pragma unroll
        for (int u = 0; u < 4; ++u) {
            int g4 = min(tb4 + u * 64 + lane, maxidx4);
            async_ld16(x + (size_t)g4 * 4, dst + u * 256);
        }
    }
    asm volatile("s_waitcnt vmcnt(0)" ::: "memory");

    if (tid < HD) { hs[tid] = 0.0f; cs[tid] = 0.0f; rs[tid] = 0.0f; }
    __syncthreads();

    for (int step = 0; step < NSTEPS; ++step) {
        // ---- LSTM cell: gates = W_ih*[h|r] + W_hh*h + biases ----
        if (step == 0) {
            // q_star = h = 0 -> gates are pure bias
            if (tid < 256) gates[tid] = b_ih[tid] + b_hh[tid];
        } else {
            float acc = 0.0f;
            if (tid < 256) {
                acc = b_ih[tid] + b_hh[tid];
                const float4* w = (const float4*)(W_ih + tid * 128);
                const float4* hq = (const float4*)hs;
                const float4* rq = (const float4*)rs;
#pragma unroll
                for (int k = 0; k < 16; ++k) {
                    float4 ww = w[k]; float4 v = hq[k];
                    acc = fmaf(ww.x, v.x, acc); acc = fmaf(ww.y, v.y, acc);
                    acc = fmaf(ww.z, v.z, acc); acc = fmaf(ww.w, v.w, acc);
                }
#pragma unroll
                for (int k = 0; k < 16; ++k) {
                    float4 ww = w[16 + k]; float4 v = rq[k];
                    acc = fmaf(ww.x, v.x, acc); acc = fmaf(ww.y, v.y, acc);
                    acc = fmaf(ww.z, v.z, acc); acc = fmaf(ww.w, v.w, acc);
                }
            } else {
                int j = tid - 256;
                float a2 = 0.0f;
                const float4* w = (const float4*)(W_hh + j * 64);
                const float4* hq = (const float4*)hs;
#pragma unroll
                for (int k = 0; k < 16; ++k) {
                    float4 ww = w[k]; float4 v = hq[k];
                    a2 = fmaf(ww.x, v.x, a2); a2 = fmaf(ww.y, v.y, a2);
                    a2 = fmaf(ww.z, v.z, a2); a2 = fmaf(ww.w, v.w, a2);
                }
                gpart[j] = a2;
            }
            __syncthreads();
            if (tid < 256) gates[tid] = acc + gpart[tid];
        }
        __syncthreads();

        if (tid < HD) {
            float ig = sigmoidf_(gates[tid]);
            float fg = sigmoidf_(gates[tid + 64]);
            float gg = tanhf(gates[tid + 128]);
            float og = sigmoidf_(gates[tid + 192]);
            float cp = (step == 0) ? 0.0f : cs[tid];
            float cn = fmaf(fg, cp, ig * gg);
            cs[tid] = cn;
            hs[tid] = og * tanhf(cn);
        }
        __syncthreads();

        // ---- attention over this graph's nodes (q = h), from LDS + registers ----
        float4 q4 = *(const float4*)(hs + fc * 4);
        float mm[4], ss[4];
        float4 rr[4];
#pragma unroll
        for (int u = 0; u < 4; ++u) {
            mm[u] = -FLT_MAX; ss[u] = 0.0f;
            rr[u] = make_float4(0.0f, 0.0f, 0.0f, 0.0f);
        }

        // LDS-cached tiles (disjoint per wave)
        for (int t = wv; t < ltiles; t += 8) {
            const float* bt = xl + t * 1024;
            int nbase = t * 16;
#pragma unroll
            for (int u = 0; u < 4; ++u) {
                float4 xv = *(const float4*)(bt + u * 256 + grp * 64 + fc * 4);
                ONLINE_UPD(u, xv, nbase + u * 4 + grp);
            }
        }
        // register-cached tiles
#pragma unroll
        for (int j = 0; j < RT2; ++j) {
            int t = LT + wv + 8 * j;
            if (t < ntiles) {
                int nbase = t * 16;
                ONLINE_UPD(0, xr[4 * j + 0], nbase + 0 * 4 + grp);
                ONLINE_UPD(1, xr[4 * j + 1], nbase + 1 * 4 + grp);
                ONLINE_UPD(2, xr[4 * j + 2], nbase + 2 * 4 + grp);
                ONLINE_UPD(3, xr[4 * j + 3], nbase + 3 * 4 + grp);
            }
        }
        // overflow tiles beyond both caches (very rare): stream from global (L3-hot)
        for (int t = LT + 8 * RT2 + wv; t < ntiles; t += 8) {
            int tb4 = (s0 + t * 16) * 16;
            int nbase = t * 16;
#pragma unroll
            for (int u = 0; u < 4; ++u) {
                int g4 = min(tb4 + u * 64 + lane, maxidx4);
                float4 xv = *(const float4*)(x + (size_t)g4 * 4);
                ONLINE_UPD(u, xv, nbase + u * 4 + grp);
            }
        }

        // merge the 4 accumulator sets within the lane
        float m = mm[0], sum = ss[0];
        float4 r4 = rr[0];
#pragma unroll
        for (int u = 1; u < 4; ++u) {
            float nm = fmaxf(m, mm[u]);
            float s1 = __expf(m - nm);
            float s2 = __expf(mm[u] - nm);
            sum = sum * s1 + ss[u] * s2;
            r4.x = r4.x * s1 + rr[u].x * s2;
            r4.y = r4.y * s1 + rr[u].y * s2;
            r4.z = r4.z * s1 + rr[u].z * s2;
            r4.w = r4.w * s1 + rr[u].w * s2;
            m = nm;
        }
        // merge the 4 node-subgroups within the wave (lanes with equal fc)
#pragma unroll
        for (int off = 16; off < 64; off <<= 1) {
            float om = __shfl_xor(m, off);
            float os = __shfl_xor(sum, off);
            float ox = __shfl_xor(r4.x, off);
            float oy = __shfl_xor(r4.y, off);
            float oz = __shfl_xor(r4.z, off);
            float ow = __shfl_xor(r4.w, off);
            float nm = fmaxf(m, om);
            float s1 = __expf(m - nm);
            float s2 = __expf(om - nm);
            sum = sum * s1 + os * s2;
            r4.x = r4.x * s1 + ox * s2;
            r4.y = r4.y * s1 + oy * s2;
            r4.z = r4.z * s1 + oz * s2;
            r4.w = r4.w * s1 + ow * s2;
            m = nm;
        }
        if (lane < 16) {
            if (lane == 0) { lm[wv] = m; ls[wv] = sum; }
            *(float4*)&lr[wv][lane * 4] = r4;
        }
        __syncthreads();

        // merge 8 wave partials -> normalized r (stays in LDS)
        if (tid < HD) {
            float M = lm[0];
#pragma unroll
            for (int w = 1; w < 8; ++w) M = fmaxf(M, lm[w]);
            float S = 0.0f, rf = 0.0f;
#pragma unroll
            for (int w = 0; w < 8; ++w) {
                float ww = __expf(lm[w] - M);
                S = fmaf(ls[w], ww, S);
                rf = fmaf(lr[w][tid], ww, rf);
            }
            rs[tid] = rf / fmaxf(S, 1e-16f);
        }
        __syncthreads();
    }

    // ---- MLP head: out = relu([h|r] @ W1^T + b1) @ W2^T + b2 ----
    if (tid < 256) {
        float acc = b1[tid];
        const float4* w = (const float4*)(W1 + tid * 128);
        const float4* hq = (const float4*)hs;
        const float4* rq = (const float4*)rs;
#pragma unroll
        for (int k = 0; k < 16; ++k) {
            float4 ww = w[k]; float4 v = hq[k];
            acc = fmaf(ww.x, v.x, acc); acc = fmaf(ww.y, v.y, acc);
            acc = fmaf(ww.z, v.z, acc); acc = fmaf(ww.w, v.w, acc);
        }
#pragma unroll
        for (int k = 0; k < 16; ++k) {
            float4 ww = w[16 + k]; float4 v = rq[k];
            acc = fmaf(ww.x, v.x, acc); acc = fmaf(ww.y, v.y, acc);
            acc = fmaf(ww.z, v.z, acc); acc = fmaf(ww.w, v.w, acc);
        }
        gates[tid] = fmaxf(acc, 0.0f);   // reuse as hidden activations
    }
    __syncthreads();
    if (tid < 128) {
        float acc = b2[tid];
        const float4* w = (const float4*)(W2 + tid * 256);
        const float4* hq = (const float4*)gates;
#pragma unroll 8
        for (int k = 0; k < 64; ++k) {
            float4 ww = w[k]; float4 v = hq[k];
            acc = fmaf(ww.x, v.x, acc); acc = fmaf(ww.y, v.y, acc);
            acc = fmaf(ww.z, v.z, acc); acc = fmaf(ww.w, v.w, acc);
        }
        out[b * 128 + tid] = acc;
    }
}

extern "C" void kernel_launch(void* const* d_in, const int* in_sizes, int n_in,
                              void* d_out, int out_size, void* d_ws, size_t ws_size,
                              hipStream_t stream) {
    const float* x     = (const float*)d_in[0];   // [N,64]
    const int*   batch = (const int*)d_in[1];     // [N] sorted
    const float* W_ih  = (const float*)d_in[2];   // [256,128]
    const float* W_hh  = (const float*)d_in[3];   // [256,64]
    const float* b_ih  = (const float*)d_in[4];
    const float* b_hh  = (const float*)d_in[5];
    const float* W1    = (const float*)d_in[6];   // [256,128]
    const float* b1    = (const float*)d_in[7];
    const float* W2    = (const float*)d_in[8];   // [128,256]
    const float* b2    = (const float*)d_in[9];
    float* out = (float*)d_out;
    const int N = in_sizes[1];

    int* seg = (int*)d_ws;   // NB+1 ints

    seg_bounds_kernel<<<(N + 255) / 256, 256, 0, stream>>>(batch, seg, N);
    set2set_fused_kernel<<<NB, 512, 0, stream>>>(x, seg, W_ih, W_hh, b_ih, b_hh,
                                                 W1, b1, W2, b2, out);
}